// Round 3
// baseline (169.653 us; speedup 1.0000x reference)
//
#include <hip/hip_runtime.h>

// kp_loss: result = sum_{b,k} exp(-||out[b,k]-tgt[b,k]||^2 / 2) / B
// B=8192, K=2048 -> 16.7M keypoints, 268 MB fp32 input, scalar output.
// Stream is at ~6 TB/s effective (50% L3-hit mix) -> near roofline.
// This round: fuse the final reduction via last-block-done to kill the
// second kernel launch (~3-5 us of the 49.3 us total).

#define KP_B 8192

__global__ __launch_bounds__(256) void kp_loss_kernel(
    const float4* __restrict__ out4,
    const float4* __restrict__ tgt4,
    float* __restrict__ partial,
    unsigned int* __restrict__ counter,
    float* __restrict__ result,
    int n4)
{
    int tid = blockIdx.x * blockDim.x + threadIdx.x;
    int stride = gridDim.x * blockDim.x;

    float acc0 = 0.0f, acc1 = 0.0f, acc2 = 0.0f, acc3 = 0.0f;

    int i = tid;
    for (; i + 3 * stride < n4; i += 4 * stride) {
        float4 o0 = out4[i];
        float4 t0 = tgt4[i];
        float4 o1 = out4[i + stride];
        float4 t1 = tgt4[i + stride];
        float4 o2 = out4[i + 2 * stride];
        float4 t2 = tgt4[i + 2 * stride];
        float4 o3 = out4[i + 3 * stride];
        float4 t3 = tgt4[i + 3 * stride];

        {
            float dx = o0.x - t0.x, dy = o0.y - t0.y;
            float dz = o0.z - t0.z, dw = o0.w - t0.w;
            acc0 += __expf(-0.5f * (dx * dx + dy * dy));
            acc0 += __expf(-0.5f * (dz * dz + dw * dw));
        }
        {
            float dx = o1.x - t1.x, dy = o1.y - t1.y;
            float dz = o1.z - t1.z, dw = o1.w - t1.w;
            acc1 += __expf(-0.5f * (dx * dx + dy * dy));
            acc1 += __expf(-0.5f * (dz * dz + dw * dw));
        }
        {
            float dx = o2.x - t2.x, dy = o2.y - t2.y;
            float dz = o2.z - t2.z, dw = o2.w - t2.w;
            acc2 += __expf(-0.5f * (dx * dx + dy * dy));
            acc2 += __expf(-0.5f * (dz * dz + dw * dw));
        }
        {
            float dx = o3.x - t3.x, dy = o3.y - t3.y;
            float dz = o3.z - t3.z, dw = o3.w - t3.w;
            acc3 += __expf(-0.5f * (dx * dx + dy * dy));
            acc3 += __expf(-0.5f * (dz * dz + dw * dw));
        }
    }
    for (; i < n4; i += stride) {
        float4 o = out4[i];
        float4 t = tgt4[i];
        float dx = o.x - t.x, dy = o.y - t.y;
        float dz = o.z - t.z, dw = o.w - t.w;
        acc0 += __expf(-0.5f * (dx * dx + dy * dy));
        acc0 += __expf(-0.5f * (dz * dz + dw * dw));
    }

    float acc = (acc0 + acc1) + (acc2 + acc3);

    // wave-64 butterfly reduce
    #pragma unroll
    for (int off = 32; off > 0; off >>= 1)
        acc += __shfl_down(acc, off, 64);

    __shared__ float wsum[4];
    __shared__ int s_last;
    int lane = threadIdx.x & 63;
    int wave = threadIdx.x >> 6;
    if (lane == 0) wsum[wave] = acc;
    __syncthreads();

    if (threadIdx.x == 0) {
        float bsum = wsum[0] + wsum[1] + wsum[2] + wsum[3];
        // device-scope release store so other XCDs see it
        __hip_atomic_store(&partial[blockIdx.x], bsum,
                           __ATOMIC_RELEASE, __HIP_MEMORY_SCOPE_AGENT);
        unsigned int prev = __hip_atomic_fetch_add(counter, 1u,
                           __ATOMIC_ACQ_REL, __HIP_MEMORY_SCOPE_AGENT);
        s_last = (prev == (unsigned int)(gridDim.x - 1)) ? 1 : 0;
    }
    __syncthreads();

    if (s_last) {
        // last block reduces all partials (device-scope acquire loads,
        // fixed summation order -> deterministic)
        float facc = 0.0f;
        for (int j = threadIdx.x; j < (int)gridDim.x; j += blockDim.x)
            facc += __hip_atomic_load(&partial[j],
                        __ATOMIC_ACQUIRE, __HIP_MEMORY_SCOPE_AGENT);
        #pragma unroll
        for (int off = 32; off > 0; off >>= 1)
            facc += __shfl_down(facc, off, 64);
        __syncthreads();  // wsum reuse
        if (lane == 0) wsum[wave] = facc;
        __syncthreads();
        if (threadIdx.x == 0) {
            result[0] = (wsum[0] + wsum[1] + wsum[2] + wsum[3])
                        * (1.0f / (float)KP_B);
        }
    }
}

extern "C" void kernel_launch(void* const* d_in, const int* in_sizes, int n_in,
                              void* d_out, int out_size, void* d_ws, size_t ws_size,
                              hipStream_t stream)
{
    const float4* out4 = (const float4*)d_in[0];
    const float4* tgt4 = (const float4*)d_in[1];
    float* result = (float*)d_out;

    // workspace layout: [0] counter (4B, aligned up to 16), then partials
    unsigned int* counter = (unsigned int*)d_ws;
    float* partial = (float*)((char*)d_ws + 16);

    const int n_floats = in_sizes[0];          // 8192*2048*2 = 33,554,432
    const int n4 = n_floats / 4;               // 8,388,608 float4 pairs

    const int block = 256;
    const int grid = 2048;

    // zero the arrival counter each call (capture-safe stream memset)
    hipMemsetAsync(counter, 0, sizeof(unsigned int), stream);

    kp_loss_kernel<<<grid, block, 0, stream>>>(out4, tgt4, partial, counter,
                                               result, n4);
}

// Round 4
// 65.584 us; speedup vs baseline: 2.5868x; 2.5868x over previous
//
#include <hip/hip_runtime.h>

// kp_loss: result = sum_{b,k} exp(-||out[b,k]-tgt[b,k]||^2 / 2) / B
// B=8192, K=2048 -> 16.7M keypoints, 268 MB fp32 input, scalar output.
// R3 lesson: agent-scope ordered atomics (release/acquire) trigger per-block
// L2 writeback/invalidate storms -> 3x stream slowdown. Plain device-scope
// atomicAdd is a hardware L2 atomic: cheap. Single kernel, one atomicAdd
// per block, d_out zeroed via async memset each call.

#define KP_B 8192

__global__ __launch_bounds__(256) void kp_loss_kernel(
    const float4* __restrict__ out4,
    const float4* __restrict__ tgt4,
    float* __restrict__ result,
    int n4)
{
    int tid = blockIdx.x * blockDim.x + threadIdx.x;
    int stride = gridDim.x * blockDim.x;

    float acc = 0.0f;
    for (int i = tid; i < n4; i += stride) {
        float4 o = out4[i];
        float4 t = tgt4[i];
        float dx0 = o.x - t.x, dy0 = o.y - t.y;
        float dx1 = o.z - t.z, dy1 = o.w - t.w;
        float s0 = dx0 * dx0 + dy0 * dy0;
        float s1 = dx1 * dx1 + dy1 * dy1;
        acc += __expf(-0.5f * s0);
        acc += __expf(-0.5f * s1);
    }

    // wave-64 butterfly reduce
    #pragma unroll
    for (int off = 32; off > 0; off >>= 1)
        acc += __shfl_down(acc, off, 64);

    __shared__ float wsum[4];
    int lane = threadIdx.x & 63;
    int wave = threadIdx.x >> 6;
    if (lane == 0) wsum[wave] = acc;
    __syncthreads();
    if (threadIdx.x == 0) {
        float bsum = wsum[0] + wsum[1] + wsum[2] + wsum[3];
        // plain device-scope HW atomic (no fences, no L2 flush)
        atomicAdd(result, bsum * (1.0f / (float)KP_B));
    }
}

extern "C" void kernel_launch(void* const* d_in, const int* in_sizes, int n_in,
                              void* d_out, int out_size, void* d_ws, size_t ws_size,
                              hipStream_t stream)
{
    const float4* out4 = (const float4*)d_in[0];
    const float4* tgt4 = (const float4*)d_in[1];
    float* result = (float*)d_out;

    const int n_floats = in_sizes[0];          // 8192*2048*2 = 33,554,432
    const int n4 = n_floats / 4;               // 8,388,608 float4 pairs

    const int block = 256;
    const int grid = 2048;                     // 8 blocks/CU, 16 f4/thread

    // zero the scalar output each call (replays accumulate via atomicAdd)
    hipMemsetAsync(result, 0, sizeof(float), stream);

    kp_loss_kernel<<<grid, block, 0, stream>>>(out4, tgt4, result, n4);
}

// Round 5
// 50.285 us; speedup vs baseline: 3.3738x; 1.3042x over previous
//
#include <hip/hip_runtime.h>

// kp_loss: result = sum_{b,k} exp(-||out[b,k]-tgt[b,k]||^2 / 2) / B
// B=8192, K=2048 -> 268 MB fp32 input, scalar output.
//
// R3 lesson: ordered agent-scope atomics -> L2 flush storm (3x slower).
// R4 lesson: 2048 same-address atomicAdds serialize (~16 us tail).
//   -> keep R1's two-kernel structure (proven 49.3 us).
// R5 lever: working set (268 MB) slightly over-spills the 256 MB L3 ->
//   LRU thrash, 134 MB/replay from HBM. Pin 7/8 of the stream (235 MB)
//   via normal loads; read the last 1/8 (33 MB) with non-temporal
//   (no-allocate) loads so it never evicts the resident set.

#define KP_B 8192

typedef float f4v __attribute__((ext_vector_type(4)));

__global__ __launch_bounds__(256) void kp_partial_kernel(
    const f4v* __restrict__ out4,
    const f4v* __restrict__ tgt4,
    float* __restrict__ partial,
    int cut4, int n4)
{
    int tid = blockIdx.x * blockDim.x + threadIdx.x;
    int stride = gridDim.x * blockDim.x;

    float acc = 0.0f;

    // cached region [0, cut4): normal loads -> stays L3-resident across replays
    for (int i = tid; i < cut4; i += stride) {
        f4v o = out4[i];
        f4v t = tgt4[i];
        float dx0 = o.x - t.x, dy0 = o.y - t.y;
        float dx1 = o.z - t.z, dy1 = o.w - t.w;
        acc += __expf(-0.5f * (dx0 * dx0 + dy0 * dy0));
        acc += __expf(-0.5f * (dx1 * dx1 + dy1 * dy1));
    }

    // streaming region [cut4, n4): non-temporal loads -> no L3 allocation
    for (int i = cut4 + tid; i < n4; i += stride) {
        f4v o = __builtin_nontemporal_load(&out4[i]);
        f4v t = __builtin_nontemporal_load(&tgt4[i]);
        float dx0 = o.x - t.x, dy0 = o.y - t.y;
        float dx1 = o.z - t.z, dy1 = o.w - t.w;
        acc += __expf(-0.5f * (dx0 * dx0 + dy0 * dy0));
        acc += __expf(-0.5f * (dx1 * dx1 + dy1 * dy1));
    }

    // wave-64 butterfly reduce
    #pragma unroll
    for (int off = 32; off > 0; off >>= 1)
        acc += __shfl_down(acc, off, 64);

    __shared__ float wsum[4];
    int lane = threadIdx.x & 63;
    int wave = threadIdx.x >> 6;
    if (lane == 0) wsum[wave] = acc;
    __syncthreads();
    if (threadIdx.x == 0) {
        partial[blockIdx.x] = wsum[0] + wsum[1] + wsum[2] + wsum[3];
    }
}

__global__ __launch_bounds__(256) void kp_final_kernel(
    const float* __restrict__ partial,
    float* __restrict__ result,
    int n)
{
    float acc = 0.0f;
    for (int i = threadIdx.x; i < n; i += 256)
        acc += partial[i];

    #pragma unroll
    for (int off = 32; off > 0; off >>= 1)
        acc += __shfl_down(acc, off, 64);

    __shared__ float wsum[4];
    int lane = threadIdx.x & 63;
    int wave = threadIdx.x >> 6;
    if (lane == 0) wsum[wave] = acc;
    __syncthreads();
    if (threadIdx.x == 0) {
        result[0] = (wsum[0] + wsum[1] + wsum[2] + wsum[3]) * (1.0f / (float)KP_B);
    }
}

extern "C" void kernel_launch(void* const* d_in, const int* in_sizes, int n_in,
                              void* d_out, int out_size, void* d_ws, size_t ws_size,
                              hipStream_t stream)
{
    const f4v* out4 = (const f4v*)d_in[0];
    const f4v* tgt4 = (const f4v*)d_in[1];
    float* result = (float*)d_out;
    float* partial = (float*)d_ws;

    const int n_floats = in_sizes[0];          // 8192*2048*2 = 33,554,432
    const int n4 = n_floats / 4;               // 8,388,608 float4 pairs
    const int cut4 = (int)(((long long)n4 * 7) / 8);  // 7/8 cached ~ 235 MB

    const int block = 256;
    const int grid = 2048;

    kp_partial_kernel<<<grid, block, 0, stream>>>(out4, tgt4, partial, cut4, n4);
    kp_final_kernel<<<1, block, 0, stream>>>(partial, result, grid);
}

// Round 6
// 48.480 us; speedup vs baseline: 3.4995x; 1.0372x over previous
//
#include <hip/hip_runtime.h>

// kp_loss: result = sum_{b,k} exp(-||out[b,k]-tgt[b,k]||^2 / 2) / B
// B=8192, K=2048 -> 16.7M keypoints, 268 MB fp32 input, scalar output.
// Pure streaming reduction. Best-known structure (R1): grid-stride float4
// stream -> per-block partial -> tiny final kernel.
//
// Ledger: R2 unroll x4 neutral (not MLP-bound). R3 ordered agent-scope
// atomics: 3x slowdown (L2 maintenance storm). R4 same-address atomicAdd:
// +16 us serialized tail. R5 NT-load split: FETCH_SIZE unchanged (no MALL
// residency control) -> neutral. Main stream runs at ~5.9 TB/s = 93% of
// the 6.29 TB/s measured ceiling.

#define KP_B 8192

__global__ __launch_bounds__(256) void kp_partial_kernel(
    const float4* __restrict__ out4,
    const float4* __restrict__ tgt4,
    float* __restrict__ partial,
    int n4)
{
    int tid = blockIdx.x * blockDim.x + threadIdx.x;
    int stride = gridDim.x * blockDim.x;

    float acc = 0.0f;
    for (int i = tid; i < n4; i += stride) {
        float4 o = out4[i];
        float4 t = tgt4[i];
        float dx0 = o.x - t.x, dy0 = o.y - t.y;
        float dx1 = o.z - t.z, dy1 = o.w - t.w;
        float s0 = dx0 * dx0 + dy0 * dy0;
        float s1 = dx1 * dx1 + dy1 * dy1;
        acc += __expf(-0.5f * s0);
        acc += __expf(-0.5f * s1);
    }

    // wave-64 butterfly reduce
    #pragma unroll
    for (int off = 32; off > 0; off >>= 1)
        acc += __shfl_down(acc, off, 64);

    __shared__ float wsum[4];
    int lane = threadIdx.x & 63;
    int wave = threadIdx.x >> 6;
    if (lane == 0) wsum[wave] = acc;
    __syncthreads();
    if (threadIdx.x == 0) {
        partial[blockIdx.x] = wsum[0] + wsum[1] + wsum[2] + wsum[3];
    }
}

__global__ __launch_bounds__(256) void kp_final_kernel(
    const float4* __restrict__ partial4,
    float* __restrict__ result,
    int n4p)   // number of float4s (grid/4)
{
    float acc = 0.0f;
    for (int i = threadIdx.x; i < n4p; i += 256) {
        float4 p = partial4[i];
        acc += (p.x + p.y) + (p.z + p.w);
    }

    #pragma unroll
    for (int off = 32; off > 0; off >>= 1)
        acc += __shfl_down(acc, off, 64);

    __shared__ float wsum[4];
    int lane = threadIdx.x & 63;
    int wave = threadIdx.x >> 6;
    if (lane == 0) wsum[wave] = acc;
    __syncthreads();
    if (threadIdx.x == 0) {
        result[0] = (wsum[0] + wsum[1] + wsum[2] + wsum[3]) * (1.0f / (float)KP_B);
    }
}

extern "C" void kernel_launch(void* const* d_in, const int* in_sizes, int n_in,
                              void* d_out, int out_size, void* d_ws, size_t ws_size,
                              hipStream_t stream)
{
    const float4* out4 = (const float4*)d_in[0];
    const float4* tgt4 = (const float4*)d_in[1];
    float* result = (float*)d_out;
    float* partial = (float*)d_ws;

    const int n_floats = in_sizes[0];          // 8192*2048*2 = 33,554,432
    const int n4 = n_floats / 4;               // 8,388,608 float4 pairs

    const int block = 256;
    const int grid = 2048;                     // 8192 waves = full subscription

    kp_partial_kernel<<<grid, block, 0, stream>>>(out4, tgt4, partial, n4);
    kp_final_kernel<<<1, block, 0, stream>>>((const float4*)partial, result,
                                             grid / 4);
}